// Round 1
// baseline (953.165 us; speedup 1.0000x reference)
//
#include <hip/hip_runtime.h>
#include <stdint.h>

typedef unsigned short u16;
typedef __attribute__((ext_vector_type(8))) short short8;
typedef __attribute__((ext_vector_type(4))) short short4v;
typedef __attribute__((ext_vector_type(4))) float floatx4;

#define T_DIM 2048
#define NH    16
#define HD    128
#define H_DIM 2048
#define I_DIM 8192
#define NCOL1 22528   // 3H + 2I
#define NCOL2 10240   // H + I

__device__ __forceinline__ float bf2f(u16 b) {
  union { uint32_t u; float f; } x; x.u = ((uint32_t)b) << 16; return x.f;
}
__device__ __forceinline__ u16 f2bf(float f) {
  union { float f; uint32_t u; } x; x.f = f;
  uint32_t r = x.u + 0x7fffu + ((x.u >> 16) & 1u);
  return (u16)(r >> 16);
}

__device__ __forceinline__ void gl_lds16(const void* g, void* l) {
  __builtin_amdgcn_global_load_lds((const __attribute__((address_space(1))) void*)g,
                                   (__attribute__((address_space(3))) void*)l, 16, 0, 0);
}

__device__ __forceinline__ floatx4 mfma32(short8 a, short8 b, floatx4 c) {
  return __builtin_amdgcn_mfma_f32_16x16x32_bf16(a, b, c, 0, 0, 0);
}
__device__ __forceinline__ floatx4 mfma16(short4v a, short4v b, floatx4 c) {
#if __has_builtin(__builtin_amdgcn_mfma_f32_16x16x16bf16_1k)
  return __builtin_amdgcn_mfma_f32_16x16x16bf16_1k(a, b, c, 0, 0, 0);
#else
  asm volatile("v_mfma_f32_16x16x16_bf16 %0, %1, %2, %0" : "+v"(c) : "v"(a), "v"(b));
  return c;
#endif
}

// ---------------- RMSNorm + age override -> bf16 ----------------
__global__ __launch_bounds__(256) void rmsnorm_k(
    const float* __restrict__ x, const float* __restrict__ ages,
    const float* __restrict__ w, u16* __restrict__ xn) {
  int t = blockIdx.x, tid = threadIdx.x;
  const float* xr = x + (size_t)t * H_DIM;
  floatx4 a = *(const floatx4*)(xr + tid * 8);
  floatx4 b = *(const floatx4*)(xr + tid * 8 + 4);
  float ss = a[0]*a[0]+a[1]*a[1]+a[2]*a[2]+a[3]*a[3]
           + b[0]*b[0]+b[1]*b[1]+b[2]*b[2]+b[3]*b[3];
#pragma unroll
  for (int off = 32; off >= 1; off >>= 1) ss += __shfl_xor(ss, off);
  __shared__ float red[4];
  if ((tid & 63) == 0) red[tid >> 6] = ss;
  __syncthreads();
  float tot = red[0] + red[1] + red[2] + red[3];
  float rms = rsqrtf(tot * (1.0f / H_DIM) + 1e-6f);
  const float* wr = w + tid * 8;
  float v[8] = {a[0],a[1],a[2],a[3],b[0],b[1],b[2],b[3]};
  short8 o;
#pragma unroll
  for (int i = 0; i < 8; ++i) o[i] = (short)f2bf(v[i] * rms * wr[i]);
  if (tid == 255) {           // covers cols 2040..2047
    float ag = ages[t];
    o[6] = (short)f2bf(ag);
    o[7] = (short)f2bf(ag * ag);
  }
  *(short8*)(xn + (size_t)t * H_DIM + tid * 8) = o;
}

// ------------- fp32 (K,N) -> bf16 (N,K) transpose ---------------
__global__ __launch_bounds__(256) void transpose_f32_bf16(
    const float* __restrict__ in, u16* __restrict__ out, int K, int N) {
  __shared__ float tile[32][33];
  int n0 = blockIdx.x * 32, k0 = blockIdx.y * 32;
  int c = threadIdx.x & 31, r = threadIdx.x >> 5;
#pragma unroll
  for (int i = 0; i < 4; ++i) {
    int kk = r + i * 8;
    tile[c][kk] = in[(size_t)(k0 + kk) * N + n0 + c];
  }
  __syncthreads();
#pragma unroll
  for (int i = 0; i < 4; ++i) {
    int nn = r + i * 8;
    out[(size_t)(n0 + nn) * K + k0 + c] = f2bf(tile[nn][c]);
  }
}

// ------------- bf16 GEMM, B^T (N-major) input, 128x128 tile ------
// C[m][n] = sum_k A[m][k]*Bt[n][k] + bias[n].  OUTF: 0 -> bf16 out, 1 -> f32 out
template<int OUTF>
__global__ __launch_bounds__(256, 2) void gemm_bt(
    const u16* __restrict__ A, const u16* __restrict__ B,
    const float* __restrict__ bias, void* __restrict__ Cout,
    int M, int N, int K) {
  __shared__ u16 As[4096];
  __shared__ u16 Bs[4096];
  int nbn = N >> 7;
  int nwg = (M >> 7) * nbn;
  int bid = blockIdx.x;
  int swz = (bid & 7) * (nwg >> 3) + (bid >> 3);   // XCD swizzle (nwg%8==0)
  int bm = swz / nbn, bn = swz % nbn;
  int tid = threadIdx.x, lane = tid & 63;
  int wr = tid >> 7, wc = (tid >> 6) & 1;
  int lq = lane & 15, lg = lane >> 4;

  int r0 = tid >> 2, kc0 = (tid & 3) << 3;
  const u16* Ag0 = A + (size_t)(bm * 128 + r0) * K + kc0;
  const u16* Ag1 = Ag0 + (size_t)64 * K;
  const u16* Bg0 = B + (size_t)(bn * 128 + r0) * K + kc0;
  const u16* Bg1 = Bg0 + (size_t)64 * K;
  u16* As0 = As + tid * 8;
  u16* As1 = As + 2048 + tid * 8;
  u16* Bs0 = Bs + tid * 8;
  u16* Bs1 = Bs + 2048 + tid * 8;

  const u16* Ard = As + (wr * 64 + lq) * 32 + lg * 8;
  const u16* Brd = Bs + (wc * 64 + lq) * 32 + lg * 8;

  floatx4 acc[4][4] = {};

  for (int kt = 0; kt < K; kt += 32) {
    __syncthreads();
    gl_lds16(Ag0 + kt, As0);
    gl_lds16(Ag1 + kt, As1);
    gl_lds16(Bg0 + kt, Bs0);
    gl_lds16(Bg1 + kt, Bs1);
    __syncthreads();
    short8 af[4], bfr[4];
#pragma unroll
    for (int i = 0; i < 4; ++i) af[i]  = *(const short8*)(Ard + i * 512);
#pragma unroll
    for (int i = 0; i < 4; ++i) bfr[i] = *(const short8*)(Brd + i * 512);
#pragma unroll
    for (int mi = 0; mi < 4; ++mi)
#pragma unroll
      for (int ni = 0; ni < 4; ++ni)
        acc[mi][ni] = mfma32(af[mi], bfr[ni], acc[mi][ni]);
  }

#pragma unroll
  for (int mi = 0; mi < 4; ++mi) {
#pragma unroll
    for (int ni = 0; ni < 4; ++ni) {
      int col = bn * 128 + wc * 64 + ni * 16 + lq;
      float bv = bias[col];
#pragma unroll
      for (int j = 0; j < 4; ++j) {
        int row = bm * 128 + wr * 64 + mi * 16 + lg * 4 + j;
        float vv = acc[mi][ni][j] + bv;
        if (OUTF) ((float*)Cout)[(size_t)row * N + col] = vv;
        else      ((u16*)Cout)[(size_t)row * N + col]   = f2bf(vv);
      }
    }
  }
}

// ---- RoPE on q,k; split qkv; V stored transposed [h][d][t] ------
__global__ __launch_bounds__(256) void rope_split(
    const u16* __restrict__ tb, const float* __restrict__ sinp, const float* __restrict__ cosp,
    u16* __restrict__ qb, u16* __restrict__ kb, u16* __restrict__ vt) {
  __shared__ u16 vtile[32][130];
  int t0 = blockIdx.x * 32, h = blockIdx.y, tid = threadIdx.x;
  int r = tid >> 3, d0 = (tid & 7) << 4;
  int t = t0 + r;
  const u16* base = tb + (size_t)t * NCOL1 + 2 * I_DIM + h * HD + d0;
  const float* cp = cosp + (size_t)t * HD + d0;
  const float* sp = sinp + (size_t)t * HD + d0;
  float cv[16], sv[16];
#pragma unroll
  for (int i = 0; i < 16; i += 4) {
    *(floatx4*)(cv + i) = *(const floatx4*)(cp + i);
    *(floatx4*)(sv + i) = *(const floatx4*)(sp + i);
  }
#pragma unroll
  for (int s = 0; s < 2; ++s) {
    const u16* src = base + s * (NH * HD);
    short8 x0 = *(const short8*)src;
    short8 x1 = *(const short8*)(src + 8);
    float xf[16];
#pragma unroll
    for (int i = 0; i < 8; ++i) { xf[i] = bf2f((u16)x0[i]); xf[8 + i] = bf2f((u16)x1[i]); }
    short8 o0, o1;
#pragma unroll
    for (int i = 0; i < 8; i += 2) {
      o0[i]     = (short)f2bf(xf[i] * cv[i] - xf[i + 1] * sv[i]);
      o0[i + 1] = (short)f2bf(xf[i + 1] * cv[i + 1] + xf[i] * sv[i + 1]);
      o1[i]     = (short)f2bf(xf[8 + i] * cv[8 + i] - xf[9 + i] * sv[8 + i]);
      o1[i + 1] = (short)f2bf(xf[9 + i] * cv[9 + i] + xf[8 + i] * sv[9 + i]);
    }
    u16* dst = (s == 0 ? qb : kb) + ((size_t)h * T_DIM + t) * HD + d0;
    *(short8*)dst = o0;
    *(short8*)(dst + 8) = o1;
  }
  short8 v0 = *(const short8*)(base + 2 * NH * HD);
  short8 v1 = *(const short8*)(base + 2 * NH * HD + 8);
#pragma unroll
  for (int i = 0; i < 8; ++i) {
    vtile[r][d0 + i]     = (u16)v0[i];
    vtile[r][d0 + 8 + i] = (u16)v1[i];
  }
  __syncthreads();
  int d = tid >> 1, th = (tid & 1) << 4;
  short8 w0, w1;
#pragma unroll
  for (int i = 0; i < 8; ++i) {
    w0[i] = (short)vtile[th + i][d];
    w1[i] = (short)vtile[th + 8 + i][d];
  }
  u16* vdst = vt + ((size_t)h * HD + d) * T_DIM + t0 + th;
  *(short8*)vdst = w0;
  *(short8*)(vdst + 8) = w1;
}

// -------------------- silu(x1)*x2 -> comb[:, H:] -----------------
__global__ __launch_bounds__(256) void silu_mul(
    const u16* __restrict__ tb, u16* __restrict__ comb) {
  int idx = blockIdx.x * 256 + threadIdx.x;
  int t = idx >> 10;
  int j = (idx & 1023) << 3;
  const u16* p1 = tb + (size_t)t * NCOL1 + j;
  const u16* p2 = p1 + I_DIM;
  short8 a = *(const short8*)p1;
  short8 b = *(const short8*)p2;
  short8 o;
#pragma unroll
  for (int i = 0; i < 8; ++i) {
    float x1 = bf2f((u16)a[i]), x2 = bf2f((u16)b[i]);
    float s = x1 / (1.0f + __expf(-x1));
    o[i] = (short)f2bf(s * x2);
  }
  *(short8*)(comb + (size_t)t * NCOL2 + H_DIM + j) = o;
}

// ------ flash attention: S^T = mfma(K,Q); PV = mfma(V^T, P^T) ----
__global__ __launch_bounds__(256) void attn_k(
    const u16* __restrict__ Q, const u16* __restrict__ K,
    const u16* __restrict__ V, const float* __restrict__ bias,
    u16* __restrict__ comb) {
  int h = blockIdx.x >> 5, qblk = blockIdx.x & 31;
  int wv = threadIdx.x >> 6, lane = threadIdx.x & 63;
  int lq = lane & 15, lg = lane >> 4;
  int q0 = qblk * 64 + wv * 16;
  const u16* Qp = Q + ((size_t)h * T_DIM + q0 + lq) * HD + lg * 8;
  const u16* Kh = K + (size_t)h * T_DIM * HD + lg * 8;
  const u16* Vh = V + ((size_t)h * HD + lq) * T_DIM + lg * 4;
  const float* Bp = bias + ((size_t)h * T_DIM + q0 + lq) * T_DIM + lg * 4;
  short8 qf[4];
#pragma unroll
  for (int t = 0; t < 4; ++t) qf[t] = *(const short8*)(Qp + t * 32);
  floatx4 o[8] = {};
  float m = -1e30f, l = 0.f;
  const float sc = 0.08838834764831845f;   // 1/sqrt(128)
  for (int s0 = 0; s0 < T_DIM; s0 += 32) {
    floatx4 st0 = {0.f,0.f,0.f,0.f}, st1 = {0.f,0.f,0.f,0.f};
    const u16* kp0 = Kh + (size_t)(s0 + lq) * HD;
    const u16* kp1 = kp0 + 16 * HD;
#pragma unroll
    for (int t = 0; t < 4; ++t) {
      st0 = mfma32(*(const short8*)(kp0 + t * 32), qf[t], st0);
      st1 = mfma32(*(const short8*)(kp1 + t * 32), qf[t], st1);
    }
    floatx4 b0 = *(const floatx4*)(Bp + s0);
    floatx4 b1 = *(const floatx4*)(Bp + s0 + 16);
    float p[8]; float tmax = -1e30f;
#pragma unroll
    for (int j = 0; j < 4; ++j) {
      p[j]     = st0[j] * sc + b0[j];
      p[4 + j] = st1[j] * sc + b1[j];
      tmax = fmaxf(tmax, fmaxf(p[j], p[4 + j]));
    }
    tmax = fmaxf(tmax, __shfl_xor(tmax, 16));
    tmax = fmaxf(tmax, __shfl_xor(tmax, 32));
    float mn = fmaxf(m, tmax);
    float alpha = __expf(m - mn);
    float rs = 0.f;
    short4v pb0, pb1;
#pragma unroll
    for (int j = 0; j < 4; ++j) {
      float e0 = __expf(p[j] - mn), e1 = __expf(p[4 + j] - mn);
      rs += e0 + e1;
      pb0[j] = (short)f2bf(e0);
      pb1[j] = (short)f2bf(e1);
    }
    rs += __shfl_xor(rs, 16);
    rs += __shfl_xor(rs, 32);
    l = l * alpha + rs; m = mn;
#pragma unroll
    for (int dt = 0; dt < 8; ++dt) o[dt] *= alpha;
#pragma unroll
    for (int dt = 0; dt < 8; ++dt) {
      short4v v0 = *(const short4v*)(Vh + (size_t)dt * 16 * T_DIM + s0);
      short4v v1 = *(const short4v*)(Vh + (size_t)dt * 16 * T_DIM + s0 + 16);
      o[dt] = mfma16(v0, pb0, o[dt]);
      o[dt] = mfma16(v1, pb1, o[dt]);
    }
  }
  float inv = 1.0f / l;
  u16* outp = comb + (size_t)(q0 + lq) * NCOL2 + h * HD + lg * 4;
#pragma unroll
  for (int dt = 0; dt < 8; ++dt) {
    short4v ov;
#pragma unroll
    for (int j = 0; j < 4; ++j) ov[j] = (short)f2bf(o[dt][j] * inv);
    *(short4v*)(outp + dt * 16) = ov;
  }
}

extern "C" void kernel_launch(void* const* d_in, const int* in_sizes, int n_in,
                              void* d_out, int out_size, void* d_ws, size_t ws_size,
                              hipStream_t stream) {
  (void)in_sizes; (void)n_in; (void)out_size; (void)ws_size;
  const float* x     = (const float*)d_in[0];
  const float* ages  = (const float*)d_in[1];
  const float* sinp  = (const float*)d_in[2];
  const float* cosp  = (const float*)d_in[3];
  const float* bias  = (const float*)d_in[4];
  const float* normw = (const float*)d_in[5];
  const float* w_in  = (const float*)d_in[6];
  const float* b_in  = (const float*)d_in[7];
  const float* w_out = (const float*)d_in[8];
  const float* b_out = (const float*)d_in[9];

  char* ws = (char*)d_ws;
  const size_t SZ_XN   = (size_t)T_DIM * H_DIM * 2;      //  8 MiB
  const size_t SZ_W1T  = (size_t)NCOL1 * H_DIM * 2;      //  88 MiB
  const size_t SZ_T    = (size_t)T_DIM * NCOL1 * 2;      //  88 MiB
  const size_t SZ_HEAD = (size_t)NH * T_DIM * HD * 2;    //   8 MiB
  u16* xn   = (u16*)(ws);
  u16* w1t  = (u16*)(ws + SZ_XN);
  u16* tb   = (u16*)(ws + SZ_XN + SZ_W1T);
  u16* qb   = (u16*)(ws + SZ_XN + SZ_W1T + SZ_T);
  u16* kb   = (u16*)(ws + SZ_XN + SZ_W1T + SZ_T + SZ_HEAD);
  u16* vt   = (u16*)(ws + SZ_XN + SZ_W1T + SZ_T + 2 * SZ_HEAD);
  u16* w2t  = (u16*)(ws + SZ_XN);                  // reuse w1t region (dead after GEMM1)
  u16* comb = (u16*)(ws + SZ_XN + (48ull << 20));  // also inside w1t region, disjoint from w2t

  rmsnorm_k<<<T_DIM, 256, 0, stream>>>(x, ages, normw, xn);
  transpose_f32_bf16<<<dim3(NCOL1 / 32, H_DIM / 32), 256, 0, stream>>>(w_in, w1t, H_DIM, NCOL1);
  gemm_bt<0><<<(T_DIM / 128) * (NCOL1 / 128), 256, 0, stream>>>(xn, w1t, b_in, tb, T_DIM, NCOL1, H_DIM);
  rope_split<<<dim3(T_DIM / 32, NH), 256, 0, stream>>>(tb, sinp, cosp, qb, kb, vt);
  silu_mul<<<(T_DIM * I_DIM) / (256 * 8), 256, 0, stream>>>(tb, comb);
  transpose_f32_bf16<<<dim3(H_DIM / 32, NCOL2 / 32), 256, 0, stream>>>(w_out, w2t, NCOL2, H_DIM);
  attn_k<<<NH * (T_DIM / 64), 256, 0, stream>>>(qb, kb, vt, bias, comb);
  gemm_bt<1><<<(T_DIM / 128) * (H_DIM / 128), 256, 0, stream>>>(comb, w2t, b_out, d_out, T_DIM, H_DIM, NCOL2);
}